// Round 1
// baseline (727.843 us; speedup 1.0000x reference)
//
#include <hip/hip_runtime.h>
#include <hip/hip_bf16.h>
#include <cstdint>
#include <cstddef>

using bf16 = __bf16;
typedef __bf16 bf16x8 __attribute__((ext_vector_type(8)));
typedef __bf16 bf16x4 __attribute__((ext_vector_type(4)));
typedef float  f32x4  __attribute__((ext_vector_type(4)));

#define DEV __device__ __forceinline__

DEV float sigmoidf_(float x) { return 1.0f / (1.0f + __expf(-x)); }

typedef __attribute__((address_space(1))) void as1_void;
typedef __attribute__((address_space(3))) void as3_void;

// async global->LDS, 16B per lane; LDS dest = wave-uniform base + lane*16
DEV void load16_lds(const void* g, void* l) {
  __builtin_amdgcn_global_load_lds((as1_void*)(void*)g, (as3_void*)l, 16, 0, 0);
}

// ---------------- kernel 1: rmsnorm -> x (bf16) ----------------
__global__ __launch_bounds__(256) void k_rms_x(const float* __restrict__ inp,
                                               const float* __restrict__ nw,
                                               bf16* __restrict__ x) {
  const int row = blockIdx.x;            // b*S + s
  const int t = threadIdx.x;
  const float* r = inp + (size_t)row * 1024 + t * 4;
  f32x4 v = *(const f32x4*)r;
  float ss = v[0]*v[0] + v[1]*v[1] + v[2]*v[2] + v[3]*v[3];
  __shared__ float red[4];
  for (int off = 32; off; off >>= 1) ss += __shfl_down(ss, off);
  if ((t & 63) == 0) red[t >> 6] = ss;
  __syncthreads();
  float tot = red[0] + red[1] + red[2] + red[3];
  float sc = rsqrtf(tot * (1.0f / 1024.0f) + 1e-5f);
  f32x4 w = *(const f32x4*)(nw + t * 4);
  bf16x4 o;
  o[0] = (bf16)(v[0] * sc * w[0]); o[1] = (bf16)(v[1] * sc * w[1]);
  o[2] = (bf16)(v[2] * sc * w[2]); o[3] = (bf16)(v[3] * sc * w[3]);
  *(bf16x4*)(x + (size_t)row * 1024 + t * 4) = o;
}

// ---------------- kernel 2: column partial sums of x ----------------
__global__ __launch_bounds__(256) void k_colsum(const bf16* __restrict__ x,
                                                float* __restrict__ part) {
  const int b = blockIdx.y, c = blockIdx.x;   // 32 chunks x 128 rows
  const int d = threadIdx.x * 4;
  f32x4 s = {0.f, 0.f, 0.f, 0.f};
  const bf16* base = x + ((size_t)b * 4096 + (size_t)c * 128) * 1024 + d;
  for (int i = 0; i < 128; ++i) {
    bf16x4 v = *(const bf16x4*)(base + (size_t)i * 1024);
    s[0] += (float)v[0]; s[1] += (float)v[1];
    s[2] += (float)v[2]; s[3] += (float)v[3];
  }
  *(f32x4*)(part + ((size_t)(b * 32 + c)) * 1024 + d) = s;
}

// ---------------- kernel 3: router logits -> softmax probs ----------------
__global__ __launch_bounds__(256) void k_router(const float* __restrict__ part,
                                                const float* __restrict__ rw,
                                                const float* __restrict__ rb,
                                                float* __restrict__ probs,
                                                float* __restrict__ aux) {
  const int t = threadIdx.x;
  __shared__ float red[4];
  __shared__ float lg[3];
  for (int b = 0; b < 8; ++b) {
    f32x4 cs = {0.f, 0.f, 0.f, 0.f};
    for (int c = 0; c < 32; ++c)
      cs += *(const f32x4*)(part + ((size_t)(b * 32 + c)) * 1024 + t * 4);
    for (int e = 0; e < 3; ++e) {
      float dot = cs[0] * rw[(t*4+0)*3+e] + cs[1] * rw[(t*4+1)*3+e]
                + cs[2] * rw[(t*4+2)*3+e] + cs[3] * rw[(t*4+3)*3+e];
      for (int off = 32; off; off >>= 1) dot += __shfl_down(dot, off);
      __syncthreads();
      if ((t & 63) == 0) red[t >> 6] = dot;
      __syncthreads();
      if (t == 0) lg[e] = (red[0]+red[1]+red[2]+red[3]) * (1.0f/4096.0f) + rb[e];
    }
    __syncthreads();
    if (t == 0) {
      float m = fmaxf(lg[0], fmaxf(lg[1], lg[2]));
      float p0 = __expf(lg[0]-m), p1 = __expf(lg[1]-m), p2 = __expf(lg[2]-m);
      float inv = 1.0f / (p0 + p1 + p2);
      probs[b*3+0] = p0*inv; probs[b*3+1] = p1*inv; probs[b*3+2] = p2*inv;
    }
    __syncthreads();
  }
  if (t == 0) *aux = 0.0f;
}

// ------- kernel 4: mix experts by probs + transpose -> [B][N][K] bf16 -------
__global__ __launch_bounds__(256) void k_mixT(const float* __restrict__ W,  // [3][1024][Ncols]
                                              const float* __restrict__ probs,
                                              bf16* __restrict__ out,       // [8][Ncols][1024]
                                              int Ncols) {
  const int b = blockIdx.z;
  const int i0 = blockIdx.y * 64;   // K dim (1024)
  const int j0 = blockIdx.x * 64;   // N dim (Ncols)
  const float p0 = probs[b*3+0], p1 = probs[b*3+1], p2 = probs[b*3+2];
  __shared__ float tile[64][68];
  const int t = threadIdx.x;
  const int jl = (t & 15) * 4;
  const size_t estr = (size_t)1024 * Ncols;
  for (int ii = 0; ii < 4; ++ii) {
    int il = (t >> 4) + ii * 16;
    const float* src = W + (size_t)(i0 + il) * Ncols + (j0 + jl);
    f32x4 v0 = *(const f32x4*)(src);
    f32x4 v1 = *(const f32x4*)(src + estr);
    f32x4 v2 = *(const f32x4*)(src + 2 * estr);
    f32x4 v = p0 * v0 + p1 * v1 + p2 * v2;
    tile[il][jl+0] = v[0]; tile[il][jl+1] = v[1];
    tile[il][jl+2] = v[2]; tile[il][jl+3] = v[3];
  }
  __syncthreads();
  bf16* ob = out + (size_t)b * Ncols * 1024;
  const int il2 = (t & 15) * 4;
  for (int jj = 0; jj < 4; ++jj) {
    int jl2 = (t >> 4) + jj * 16;
    bf16x4 o;
    o[0] = (bf16)tile[il2+0][jl2]; o[1] = (bf16)tile[il2+1][jl2];
    o[2] = (bf16)tile[il2+2][jl2]; o[3] = (bf16)tile[il2+3][jl2];
    *(bf16x4*)(ob + (size_t)(j0 + jl2) * 1024 + (i0 + il2)) = o;
  }
}

// ---------------- GEMM: C[M,N] = A[M,K] @ Bt[N,K]^T, bf16 MFMA ----------------
// EPI 0: store bf16 C.   EPI 1: store fp32 C = acc + addend.
template<int EPI>
__global__ __launch_bounds__(256) void k_gemm(const bf16* __restrict__ A,
                                              const bf16* __restrict__ Bt,
                                              const float* __restrict__ addend,
                                              void* __restrict__ Cout,
                                              int M, int N, int K) {
  const int bz = blockIdx.z;
  const int tm = blockIdx.y, tn = blockIdx.x;
  __shared__ bf16 sA[128 * 64];
  __shared__ bf16 sB[128 * 64];
  const int tid = threadIdx.x;
  const int lane = tid & 63, w = tid >> 6;
  const int wm = (w >> 1) * 64, wn = (w & 1) * 64;
  const int l15 = lane & 15, quad = lane >> 4;
  const bf16* Ab = A + (size_t)bz * M * K + (size_t)tm * 128 * K;
  const bf16* Bb = Bt + (size_t)bz * N * K + (size_t)tn * 128 * K;
  f32x4 acc[4][4] = {};

  for (int k0 = 0; k0 < K; k0 += 64) {
    // stage 128x64 A tile and 128x64 B tile; xor-swizzled k-chunks
    #pragma unroll
    for (int i = 0; i < 4; ++i) {
      const int q   = i * 256 + w * 64 + lane;
      const int row = q >> 3;
      const int kc  = (q & 7) ^ (row & 7);
      load16_lds(Ab + (size_t)row * K + k0 + kc * 8, (char*)sA + q * 16);
      load16_lds(Bb + (size_t)row * K + k0 + kc * 8, (char*)sB + q * 16);
    }
    __syncthreads();
    #pragma unroll
    for (int ks = 0; ks < 2; ++ks) {
      bf16x8 af[4], bfr[4];
      const int kc = ks * 4 + quad;
      #pragma unroll
      for (int mi = 0; mi < 4; ++mi) {
        int m = wm + mi * 16 + l15;
        af[mi] = *(const bf16x8*)(sA + (size_t)(m * 8 + (kc ^ (m & 7))) * 8);
      }
      #pragma unroll
      for (int ni = 0; ni < 4; ++ni) {
        int n = wn + ni * 16 + l15;
        bfr[ni] = *(const bf16x8*)(sB + (size_t)(n * 8 + (kc ^ (n & 7))) * 8);
      }
      #pragma unroll
      for (int mi = 0; mi < 4; ++mi)
        #pragma unroll
        for (int ni = 0; ni < 4; ++ni)
          acc[mi][ni] = __builtin_amdgcn_mfma_f32_16x16x32_bf16(
              af[mi], bfr[ni], acc[mi][ni], 0, 0, 0);
    }
    __syncthreads();
  }

  if constexpr (EPI == 0) {
    bf16* C = (bf16*)Cout + (size_t)bz * M * N;
    #pragma unroll
    for (int mi = 0; mi < 4; ++mi)
      #pragma unroll
      for (int ni = 0; ni < 4; ++ni)
        #pragma unroll
        for (int r = 0; r < 4; ++r) {
          int row = tm * 128 + wm + mi * 16 + quad * 4 + r;
          int col = tn * 128 + wn + ni * 16 + l15;
          C[(size_t)row * N + col] = (bf16)acc[mi][ni][r];
        }
  } else {
    float* C = (float*)Cout + (size_t)bz * M * N;
    const float* Ain = addend + (size_t)bz * M * N;
    #pragma unroll
    for (int mi = 0; mi < 4; ++mi)
      #pragma unroll
      for (int ni = 0; ni < 4; ++ni)
        #pragma unroll
        for (int r = 0; r < 4; ++r) {
          int row = tm * 128 + wm + mi * 16 + quad * 4 + r;
          int col = tn * 128 + wn + ni * 16 + l15;
          size_t idx = (size_t)row * N + col;
          C[idx] = acc[mi][ni][r] + Ain[idx];
        }
  }
}

// ---------------- scan helpers ----------------
DEV void ab_from(bf16 hid, bf16 gt, float& a, float& bb) {
  float z = sigmoidf_((float)gt);
  a = 1.0f - z;
  float hv = (float)hid;
  float g = (hv >= 0.0f) ? (hv + 0.5f) : sigmoidf_(hv);
  bb = z * g;
}

// pass 1: per-chunk (prodA, scanB) summaries. chunks of 64 steps.
__global__ __launch_bounds__(256) void k_scan1(const bf16* __restrict__ hg,
                                               float* __restrict__ cA,
                                               float* __restrict__ cB) {
  const int b = blockIdx.y, c = blockIdx.x;
  const int d = threadIdx.x * 4;
  f32x4 A = {1.f, 1.f, 1.f, 1.f}, Bv = {0.f, 0.f, 0.f, 0.f};
  const bf16* base = hg + ((size_t)(b * 4096 + c * 64)) * 2048 + d;
  #pragma unroll 4
  for (int i = 0; i < 64; ++i) {
    bf16x4 hid = *(const bf16x4*)(base + (size_t)i * 2048);
    bf16x4 gt  = *(const bf16x4*)(base + (size_t)i * 2048 + 1024);
    #pragma unroll
    for (int j = 0; j < 4; ++j) {
      float a, bb; ab_from(hid[j], gt[j], a, bb);
      A[j] *= a; Bv[j] = a * Bv[j] + bb;
    }
  }
  *(f32x4*)(cA + ((size_t)(b * 64 + c)) * 1024 + d) = A;
  *(f32x4*)(cB + ((size_t)(b * 64 + c)) * 1024 + d) = Bv;
}

// pass 2: chunk-level prefix; writes per-chunk entry state + new_state
__global__ __launch_bounds__(256) void k_scan2(const float* __restrict__ cA,
                                               const float* __restrict__ cB,
                                               const float* __restrict__ state,
                                               float* __restrict__ hin,
                                               float* __restrict__ ns) {
  const int gid = blockIdx.x * 256 + threadIdx.x;  // 8192 channels
  const int b = gid >> 10, d = gid & 1023;
  float h = state[gid];
  for (int c = 0; c < 64; ++c) {
    size_t idx = (((size_t)(b * 64 + c)) << 10) + d;
    hin[idx] = h;
    h = cA[idx] * h + cB[idx];
  }
  ns[gid] = h;
}

// pass 3: replay chunk with known entry state, write h (bf16)
__global__ __launch_bounds__(256) void k_scan3(const bf16* __restrict__ hg,
                                               const float* __restrict__ hin,
                                               bf16* __restrict__ hq) {
  const int b = blockIdx.y, c = blockIdx.x;
  const int d = threadIdx.x * 4;
  f32x4 h = *(const f32x4*)(hin + ((size_t)(b * 64 + c)) * 1024 + d);
  const bf16* base = hg + ((size_t)(b * 4096 + c * 64)) * 2048 + d;
  bf16* ob = hq + ((size_t)(b * 4096 + c * 64)) * 1024 + d;
  #pragma unroll 4
  for (int i = 0; i < 64; ++i) {
    bf16x4 hid = *(const bf16x4*)(base + (size_t)i * 2048);
    bf16x4 gt  = *(const bf16x4*)(base + (size_t)i * 2048 + 1024);
    bf16x4 o;
    #pragma unroll
    for (int j = 0; j < 4; ++j) {
      float a, bb; ab_from(hid[j], gt[j], a, bb);
      h[j] = a * h[j] + bb;
      o[j] = (bf16)h[j];
    }
    *(bf16x4*)(ob + (size_t)i * 1024) = o;
  }
}

extern "C" void kernel_launch(void* const* d_in, const int* in_sizes, int n_in,
                              void* d_out, int out_size, void* d_ws, size_t ws_size,
                              hipStream_t stream) {
  const float* inputs   = (const float*)d_in[0];
  const float* state    = (const float*)d_in[1];
  const float* norm_w   = (const float*)d_in[2];
  const float* router_w = (const float*)d_in[3];
  const float* router_b = (const float*)d_in[4];
  const float* w_gh     = (const float*)d_in[5];
  const float* w_out    = (const float*)d_in[6];

  float* out = (float*)d_out;
  float* new_state = out + (size_t)8 * 4096 * 1024;
  float* aux = new_state + 8 * 1024;

  char* ws = (char*)d_ws;
  size_t off = 0;
  auto alloc = [&](size_t bytes) {
    char* p = ws + off;
    off = (off + bytes + 255) & ~(size_t)255;
    return p;
  };
  bf16*  x    = (bf16*)alloc((size_t)8 * 4096 * 1024 * 2);   // 64 MB
  bf16*  hg   = (bf16*)alloc((size_t)8 * 4096 * 2048 * 2);   // 128 MB
  bf16*  hq   = (bf16*)alloc((size_t)8 * 4096 * 1024 * 2);   // 64 MB
  bf16*  WgT  = (bf16*)alloc((size_t)8 * 2048 * 1024 * 2);   // 32 MB
  bf16*  WoT  = (bf16*)alloc((size_t)8 * 1024 * 1024 * 2);   // 16 MB
  float* part = (float*)alloc((size_t)8 * 32 * 1024 * 4);    // 1 MB
  float* probs = (float*)alloc(256);
  float* cA   = (float*)alloc((size_t)8 * 64 * 1024 * 4);    // 2 MB
  float* cB   = (float*)alloc((size_t)8 * 64 * 1024 * 4);
  float* hin  = (float*)alloc((size_t)8 * 64 * 1024 * 4);
  (void)in_sizes; (void)n_in; (void)out_size; (void)ws_size;

  k_rms_x <<<32768, 256, 0, stream>>>(inputs, norm_w, x);
  k_colsum<<<dim3(32, 8), 256, 0, stream>>>(x, part);
  k_router<<<1, 256, 0, stream>>>(part, router_w, router_b, probs, aux);
  k_mixT  <<<dim3(32, 16, 8), 256, 0, stream>>>(w_gh, probs, WgT, 2048);
  k_mixT  <<<dim3(16, 16, 8), 256, 0, stream>>>(w_out, probs, WoT, 1024);
  k_gemm<0><<<dim3(16, 32, 8), 256, 0, stream>>>(x, WgT, nullptr, hg, 4096, 2048, 1024);
  k_scan1 <<<dim3(64, 8), 256, 0, stream>>>(hg, cA, cB);
  k_scan2 <<<32, 256, 0, stream>>>(cA, cB, state, hin, new_state);
  k_scan3 <<<dim3(64, 8), 256, 0, stream>>>(hg, hin, hq);
  k_gemm<1><<<dim3(8, 32, 8), 256, 0, stream>>>(hq, WoT, inputs, out, 4096, 1024, 1024);
}

// Round 2
// 689.660 us; speedup vs baseline: 1.0554x; 1.0554x over previous
//
#include <hip/hip_runtime.h>
#include <hip/hip_bf16.h>
#include <cstdint>
#include <cstddef>

using bf16 = __bf16;
typedef __bf16 bf16x8 __attribute__((ext_vector_type(8)));
typedef __bf16 bf16x4 __attribute__((ext_vector_type(4)));
typedef float  f32x4  __attribute__((ext_vector_type(4)));

#define DEV __device__ __forceinline__

DEV float sigmoidf_(float x) { return 1.0f / (1.0f + __expf(-x)); }

typedef __attribute__((address_space(1))) void as1_void;
typedef __attribute__((address_space(3))) void as3_void;

// async global->LDS, 16B per lane; LDS dest = wave-uniform base + lane*16
DEV void load16_lds(const void* g, void* l) {
  __builtin_amdgcn_global_load_lds((as1_void*)(void*)g, (as3_void*)l, 16, 0, 0);
}

// ---------------- kernel 1: rmsnorm -> x (bf16) ----------------
__global__ __launch_bounds__(256) void k_rms_x(const float* __restrict__ inp,
                                               const float* __restrict__ nw,
                                               bf16* __restrict__ x) {
  const int row = blockIdx.x;            // b*S + s
  const int t = threadIdx.x;
  const float* r = inp + (size_t)row * 1024 + t * 4;
  f32x4 v = *(const f32x4*)r;
  float ss = v[0]*v[0] + v[1]*v[1] + v[2]*v[2] + v[3]*v[3];
  __shared__ float red[4];
  for (int off = 32; off; off >>= 1) ss += __shfl_down(ss, off);
  if ((t & 63) == 0) red[t >> 6] = ss;
  __syncthreads();
  float tot = red[0] + red[1] + red[2] + red[3];
  float sc = rsqrtf(tot * (1.0f / 1024.0f) + 1e-5f);
  f32x4 w = *(const f32x4*)(nw + t * 4);
  bf16x4 o;
  o[0] = (bf16)(v[0] * sc * w[0]); o[1] = (bf16)(v[1] * sc * w[1]);
  o[2] = (bf16)(v[2] * sc * w[2]); o[3] = (bf16)(v[3] * sc * w[3]);
  *(bf16x4*)(x + (size_t)row * 1024 + t * 4) = o;
}

// ---------------- kernel 2: column partial sums of x ----------------
__global__ __launch_bounds__(256) void k_colsum(const bf16* __restrict__ x,
                                                float* __restrict__ part) {
  const int b = blockIdx.y, c = blockIdx.x;   // 32 chunks x 128 rows
  const int d = threadIdx.x * 4;
  f32x4 s = {0.f, 0.f, 0.f, 0.f};
  const bf16* base = x + ((size_t)b * 4096 + (size_t)c * 128) * 1024 + d;
  for (int i = 0; i < 128; ++i) {
    bf16x4 v = *(const bf16x4*)(base + (size_t)i * 1024);
    s[0] += (float)v[0]; s[1] += (float)v[1];
    s[2] += (float)v[2]; s[3] += (float)v[3];
  }
  *(f32x4*)(part + ((size_t)(b * 32 + c)) * 1024 + d) = s;
}

// ---------------- kernel 3: router logits -> softmax probs (1 block/batch) ----------------
__global__ __launch_bounds__(256) void k_router(const float* __restrict__ part,
                                                const float* __restrict__ rw,
                                                const float* __restrict__ rb,
                                                float* __restrict__ probs,
                                                float* __restrict__ aux) {
  const int b = blockIdx.x;
  const int t = threadIdx.x;
  __shared__ float red[4];
  __shared__ float lg[3];
  f32x4 cs = {0.f, 0.f, 0.f, 0.f};
  #pragma unroll 8
  for (int c = 0; c < 32; ++c)
    cs += *(const f32x4*)(part + ((size_t)(b * 32 + c)) * 1024 + t * 4);
  for (int e = 0; e < 3; ++e) {
    float dot = cs[0] * rw[(t*4+0)*3+e] + cs[1] * rw[(t*4+1)*3+e]
              + cs[2] * rw[(t*4+2)*3+e] + cs[3] * rw[(t*4+3)*3+e];
    for (int off = 32; off; off >>= 1) dot += __shfl_down(dot, off);
    if ((t & 63) == 0) red[t >> 6] = dot;
    __syncthreads();
    if (t == 0) lg[e] = (red[0]+red[1]+red[2]+red[3]) * (1.0f/4096.0f) + rb[e];
    __syncthreads();
  }
  if (t == 0) {
    float m = fmaxf(lg[0], fmaxf(lg[1], lg[2]));
    float p0 = __expf(lg[0]-m), p1 = __expf(lg[1]-m), p2 = __expf(lg[2]-m);
    float inv = 1.0f / (p0 + p1 + p2);
    probs[b*3+0] = p0*inv; probs[b*3+1] = p1*inv; probs[b*3+2] = p2*inv;
    if (b == 0) *aux = 0.0f;
  }
}

// ------- kernel 4: mix experts by probs + transpose -> [B][N][K] bf16 -------
__global__ __launch_bounds__(256) void k_mixT(const float* __restrict__ W,  // [3][1024][Ncols]
                                              const float* __restrict__ probs,
                                              bf16* __restrict__ out,       // [8][Ncols][1024]
                                              int Ncols) {
  const int b = blockIdx.z;
  const int i0 = blockIdx.y * 64;   // K dim (1024)
  const int j0 = blockIdx.x * 64;   // N dim (Ncols)
  const float p0 = probs[b*3+0], p1 = probs[b*3+1], p2 = probs[b*3+2];
  __shared__ float tile[64][68];
  const int t = threadIdx.x;
  const int jl = (t & 15) * 4;
  const size_t estr = (size_t)1024 * Ncols;
  for (int ii = 0; ii < 4; ++ii) {
    int il = (t >> 4) + ii * 16;
    const float* src = W + (size_t)(i0 + il) * Ncols + (j0 + jl);
    f32x4 v0 = *(const f32x4*)(src);
    f32x4 v1 = *(const f32x4*)(src + estr);
    f32x4 v2 = *(const f32x4*)(src + 2 * estr);
    f32x4 v = p0 * v0 + p1 * v1 + p2 * v2;
    tile[il][jl+0] = v[0]; tile[il][jl+1] = v[1];
    tile[il][jl+2] = v[2]; tile[il][jl+3] = v[3];
  }
  __syncthreads();
  bf16* ob = out + (size_t)b * Ncols * 1024;
  const int il2 = (t & 15) * 4;
  for (int jj = 0; jj < 4; ++jj) {
    int jl2 = (t >> 4) + jj * 16;
    bf16x4 o;
    o[0] = (bf16)tile[il2+0][jl2]; o[1] = (bf16)tile[il2+1][jl2];
    o[2] = (bf16)tile[il2+2][jl2]; o[3] = (bf16)tile[il2+3][jl2];
    *(bf16x4*)(ob + (size_t)(j0 + jl2) * 1024 + (i0 + il2)) = o;
  }
}

// ---------------- GEMM: C[M,N] = A[M,K] @ Bt[N,K]^T, bf16 MFMA ----------------
// EPI 0: GEMM1 — B rows fetched with hid/gate interleave (16-col groups: 8 hid + 8 gate);
//        epilogue computes z=sigmoid(gate), a=1-z, b=z*g(hid); writes bf16 a,b arrays.
// EPI 1: GEMM2 — epilogue re-tiles acc through LDS, adds fp32 addend, stores fp32 C
//        fully coalesced (f32x4).
template<int EPI>
__global__ __launch_bounds__(256) void k_gemm(const bf16* __restrict__ A,
                                              const bf16* __restrict__ Bt,
                                              const float* __restrict__ addend,
                                              float* __restrict__ Cout,
                                              bf16* __restrict__ pa,
                                              bf16* __restrict__ pb,
                                              int M, int N, int K) {
  const int bz = blockIdx.z;
  const int tm = blockIdx.y, tn = blockIdx.x;
  __shared__ __align__(16) char smem[32768];
  bf16* sA = (bf16*)smem;
  bf16* sB = (bf16*)(smem + 16384);
  const int tid = threadIdx.x;
  const int lane = tid & 63, w = tid >> 6;
  const int wm = (w >> 1) * 64, wn = (w & 1) * 64;
  const int l15 = lane & 15, quad = lane >> 4;
  const bf16* Ab  = A + (size_t)bz * M * K + (size_t)tm * 128 * K;
  const bf16* Btb = Bt + (size_t)bz * N * K;
  f32x4 acc[4][4] = {};

  for (int k0 = 0; k0 < K; k0 += 64) {
    #pragma unroll
    for (int i = 0; i < 4; ++i) {
      const int q   = i * 256 + w * 64 + lane;
      const int row = q >> 3;
      const int kc  = (q & 7) ^ (row & 7);
      load16_lds(Ab + (size_t)row * K + k0 + kc * 8, (char*)sA + q * 16);
      int nrow;
      if constexpr (EPI == 0) {
        const int c = tn * 128 + row;             // logical (interleaved) col
        const int kk = c >> 4, r = c & 15;
        nrow = (r < 8) ? (kk * 8 + r) : (1024 + kk * 8 + (r - 8));
      } else {
        nrow = tn * 128 + row;
      }
      load16_lds(Btb + (size_t)nrow * K + k0 + kc * 8, (char*)sB + q * 16);
    }
    __syncthreads();
    #pragma unroll
    for (int ks = 0; ks < 2; ++ks) {
      bf16x8 af[4], bfr[4];
      const int kc = ks * 4 + quad;
      #pragma unroll
      for (int mi = 0; mi < 4; ++mi) {
        int m = wm + mi * 16 + l15;
        af[mi] = *(const bf16x8*)(sA + (size_t)(m * 8 + (kc ^ (m & 7))) * 8);
      }
      #pragma unroll
      for (int ni = 0; ni < 4; ++ni) {
        int n = wn + ni * 16 + l15;
        bfr[ni] = *(const bf16x8*)(sB + (size_t)(n * 8 + (kc ^ (n & 7))) * 8);
      }
      #pragma unroll
      for (int mi = 0; mi < 4; ++mi)
        #pragma unroll
        for (int ni = 0; ni < 4; ++ni)
          acc[mi][ni] = __builtin_amdgcn_mfma_f32_16x16x32_bf16(
              af[mi], bfr[ni], acc[mi][ni], 0, 0, 0);
    }
    __syncthreads();
  }

  if constexpr (EPI == 0) {
    // fused activation; a,b are [M][1024] per batch
    bf16* Aab = pa + (size_t)bz * M * 1024;
    bf16* Bab = pb + (size_t)bz * M * 1024;
    const int jbase0 = (tn * 8 + (wn >> 4)) * 8;   // + ni*8 + (l15&7)
    #pragma unroll
    for (int mi = 0; mi < 4; ++mi)
      #pragma unroll
      for (int ni = 0; ni < 4; ++ni)
        #pragma unroll
        for (int r = 0; r < 4; ++r) {
          int srow = tm * 128 + wm + mi * 16 + quad * 4 + r;
          float v = acc[mi][ni][r];
          float pv = __shfl_xor(v, 8);
          float hid = (lane & 8) ? pv : v;
          float gt  = (lane & 8) ? v  : pv;
          float z = sigmoidf_(gt);
          float av = 1.0f - z;
          float gv = (hid >= 0.0f) ? (hid + 0.5f) : sigmoidf_(hid);
          float bv = z * gv;
          size_t oidx = (size_t)srow * 1024 + jbase0 + ni * 8 + (l15 & 7);
          if (lane & 8) Bab[oidx] = (bf16)bv;
          else          Aab[oidx] = (bf16)av;
        }
  } else {
    // LDS-retiled coalesced epilogue: 4 passes of 32 rows
    float* sC = (float*)smem;
    const int ST = 132;                       // fp32 stride, 16B-aligned rows
    float* C = Cout + (size_t)bz * M * N;
    const float* Ain = addend + (size_t)bz * M * N;
    #pragma unroll
    for (int p = 0; p < 4; ++p) {
      __syncthreads();
      if ((wm >> 6) == (p >> 1)) {
        const int m0 = (p & 1) * 2;
        #pragma unroll
        for (int mi = m0; mi < m0 + 2; ++mi)
          #pragma unroll
          for (int ni = 0; ni < 4; ++ni)
            #pragma unroll
            for (int r = 0; r < 4; ++r) {
              int lrow = mi * 16 + quad * 4 + r - (p & 1) * 32;
              sC[lrow * ST + wn + ni * 16 + l15] = acc[mi][ni][r];
            }
      }
      __syncthreads();
      #pragma unroll
      for (int i = 0; i < 4; ++i) {
        int v = i * 256 + tid;
        int rl = v >> 5, c4 = (v & 31) * 4;
        int grow = tm * 128 + p * 32 + rl;
        int gcol = tn * 128 + c4;
        f32x4 cv = *(f32x4*)(sC + rl * ST + c4);
        f32x4 ad = *(const f32x4*)(Ain + (size_t)grow * N + gcol);
        *(f32x4*)(C + (size_t)grow * N + gcol) = cv + ad;
      }
    }
  }
}

// pass 1: per-chunk (prodA, scanB) summaries. chunks of 64 steps.
__global__ __launch_bounds__(256) void k_scan1(const bf16* __restrict__ Aab,
                                               const bf16* __restrict__ Bab,
                                               float* __restrict__ cA,
                                               float* __restrict__ cB) {
  const int b = blockIdx.y, c = blockIdx.x;
  const int d = threadIdx.x * 4;
  f32x4 A = {1.f, 1.f, 1.f, 1.f}, Bv = {0.f, 0.f, 0.f, 0.f};
  const size_t base = ((size_t)(b * 4096 + c * 64)) * 1024 + d;
  #pragma unroll 4
  for (int i = 0; i < 64; ++i) {
    bf16x4 av = *(const bf16x4*)(Aab + base + (size_t)i * 1024);
    bf16x4 bv = *(const bf16x4*)(Bab + base + (size_t)i * 1024);
    #pragma unroll
    for (int j = 0; j < 4; ++j) {
      float a = (float)av[j], bb = (float)bv[j];
      A[j] *= a; Bv[j] = a * Bv[j] + bb;
    }
  }
  *(f32x4*)(cA + ((size_t)(b * 64 + c)) * 1024 + d) = A;
  *(f32x4*)(cB + ((size_t)(b * 64 + c)) * 1024 + d) = Bv;
}

// pass 2: chunk-level prefix; writes per-chunk entry state + new_state
__global__ __launch_bounds__(256) void k_scan2(const float* __restrict__ cA,
                                               const float* __restrict__ cB,
                                               const float* __restrict__ state,
                                               float* __restrict__ hin,
                                               float* __restrict__ ns) {
  const int gid = blockIdx.x * 256 + threadIdx.x;  // 8192 channels
  const int b = gid >> 10, d = gid & 1023;
  float h = state[gid];
  for (int c0 = 0; c0 < 64; c0 += 8) {
    float ar[8], br[8];
    #pragma unroll
    for (int i = 0; i < 8; ++i) {
      size_t idx = (((size_t)(b * 64 + c0 + i)) << 10) + d;
      ar[i] = cA[idx]; br[i] = cB[idx];
    }
    #pragma unroll
    for (int i = 0; i < 8; ++i) {
      size_t idx = (((size_t)(b * 64 + c0 + i)) << 10) + d;
      hin[idx] = h;
      h = ar[i] * h + br[i];
    }
  }
  ns[gid] = h;
}

// pass 3: replay chunk with known entry state, write h (bf16)
__global__ __launch_bounds__(256) void k_scan3(const bf16* __restrict__ Aab,
                                               const bf16* __restrict__ Bab,
                                               const float* __restrict__ hin,
                                               bf16* __restrict__ hq) {
  const int b = blockIdx.y, c = blockIdx.x;
  const int d = threadIdx.x * 4;
  f32x4 h = *(const f32x4*)(hin + ((size_t)(b * 64 + c)) * 1024 + d);
  const size_t base = ((size_t)(b * 4096 + c * 64)) * 1024 + d;
  bf16* ob = hq + base;
  #pragma unroll 4
  for (int i = 0; i < 64; ++i) {
    bf16x4 av = *(const bf16x4*)(Aab + base + (size_t)i * 1024);
    bf16x4 bv = *(const bf16x4*)(Bab + base + (size_t)i * 1024);
    bf16x4 o;
    #pragma unroll
    for (int j = 0; j < 4; ++j) {
      h[j] = (float)av[j] * h[j] + (float)bv[j];
      o[j] = (bf16)h[j];
    }
    *(bf16x4*)(ob + (size_t)i * 1024) = o;
  }
}

extern "C" void kernel_launch(void* const* d_in, const int* in_sizes, int n_in,
                              void* d_out, int out_size, void* d_ws, size_t ws_size,
                              hipStream_t stream) {
  const float* inputs   = (const float*)d_in[0];
  const float* state    = (const float*)d_in[1];
  const float* norm_w   = (const float*)d_in[2];
  const float* router_w = (const float*)d_in[3];
  const float* router_b = (const float*)d_in[4];
  const float* w_gh     = (const float*)d_in[5];
  const float* w_out    = (const float*)d_in[6];

  float* out = (float*)d_out;
  float* new_state = out + (size_t)8 * 4096 * 1024;
  float* aux = new_state + 8 * 1024;

  char* ws = (char*)d_ws;
  size_t off = 0;
  auto alloc = [&](size_t bytes) {
    char* p = ws + off;
    off = (off + bytes + 255) & ~(size_t)255;
    return p;
  };
  bf16*  x    = (bf16*)alloc((size_t)8 * 4096 * 1024 * 2);   // 64 MB
  bf16*  a_ar = (bf16*)alloc((size_t)8 * 4096 * 1024 * 2);   // 64 MB
  bf16*  b_ar = (bf16*)alloc((size_t)8 * 4096 * 1024 * 2);   // 64 MB
  bf16*  hq   = (bf16*)alloc((size_t)8 * 4096 * 1024 * 2);   // 64 MB
  bf16*  WgT  = (bf16*)alloc((size_t)8 * 2048 * 1024 * 2);   // 32 MB
  bf16*  WoT  = (bf16*)alloc((size_t)8 * 1024 * 1024 * 2);   // 16 MB
  float* part = (float*)alloc((size_t)8 * 32 * 1024 * 4);    // 1 MB
  float* probs = (float*)alloc(256);
  float* cA   = (float*)alloc((size_t)8 * 64 * 1024 * 4);    // 2 MB
  float* cB   = (float*)alloc((size_t)8 * 64 * 1024 * 4);
  float* hin  = (float*)alloc((size_t)8 * 64 * 1024 * 4);
  (void)in_sizes; (void)n_in; (void)out_size; (void)ws_size;

  k_rms_x <<<32768, 256, 0, stream>>>(inputs, norm_w, x);
  k_colsum<<<dim3(32, 8), 256, 0, stream>>>(x, part);
  k_router<<<8, 256, 0, stream>>>(part, router_w, router_b, probs, aux);
  k_mixT  <<<dim3(32, 16, 8), 256, 0, stream>>>(w_gh, probs, WgT, 2048);
  k_mixT  <<<dim3(16, 16, 8), 256, 0, stream>>>(w_out, probs, WoT, 1024);
  k_gemm<0><<<dim3(16, 32, 8), 256, 0, stream>>>(x, WgT, nullptr, nullptr,
                                                 a_ar, b_ar, 4096, 2048, 1024);
  k_scan1 <<<dim3(64, 8), 256, 0, stream>>>(a_ar, b_ar, cA, cB);
  k_scan2 <<<32, 256, 0, stream>>>(cA, cB, state, hin, new_state);
  k_scan3 <<<dim3(64, 8), 256, 0, stream>>>(a_ar, b_ar, hin, hq);
  k_gemm<1><<<dim3(8, 32, 8), 256, 0, stream>>>(hq, WoT, inputs, out,
                                                nullptr, nullptr, 4096, 1024, 1024);
}

// Round 3
// 642.766 us; speedup vs baseline: 1.1324x; 1.0730x over previous
//
#include <hip/hip_runtime.h>
#include <hip/hip_bf16.h>
#include <cstdint>
#include <cstddef>

using bf16 = __bf16;
typedef __bf16 bf16x8 __attribute__((ext_vector_type(8)));
typedef __bf16 bf16x4 __attribute__((ext_vector_type(4)));
typedef float  f32x4  __attribute__((ext_vector_type(4)));

#define DEV __device__ __forceinline__

DEV float sigmoidf_(float x) { return 1.0f / (1.0f + __expf(-x)); }

typedef __attribute__((address_space(1))) void as1_void;
typedef __attribute__((address_space(3))) void as3_void;

// async global->LDS, 16B per lane; LDS dest = wave-uniform base + lane*16
DEV void load16_lds(const void* g, void* l) {
  __builtin_amdgcn_global_load_lds((as1_void*)(void*)g, (as3_void*)l, 16, 0, 0);
}

// ---------------- kernel 1: rmsnorm -> x (bf16) ----------------
__global__ __launch_bounds__(256) void k_rms_x(const float* __restrict__ inp,
                                               const float* __restrict__ nw,
                                               bf16* __restrict__ x) {
  const int row = blockIdx.x;            // b*S + s
  const int t = threadIdx.x;
  const float* r = inp + (size_t)row * 1024 + t * 4;
  f32x4 v = *(const f32x4*)r;
  float ss = v[0]*v[0] + v[1]*v[1] + v[2]*v[2] + v[3]*v[3];
  __shared__ float red[4];
  for (int off = 32; off; off >>= 1) ss += __shfl_down(ss, off);
  if ((t & 63) == 0) red[t >> 6] = ss;
  __syncthreads();
  float tot = red[0] + red[1] + red[2] + red[3];
  float sc = rsqrtf(tot * (1.0f / 1024.0f) + 1e-5f);
  f32x4 w = *(const f32x4*)(nw + t * 4);
  bf16x4 o;
  o[0] = (bf16)(v[0] * sc * w[0]); o[1] = (bf16)(v[1] * sc * w[1]);
  o[2] = (bf16)(v[2] * sc * w[2]); o[3] = (bf16)(v[3] * sc * w[3]);
  *(bf16x4*)(x + (size_t)row * 1024 + t * 4) = o;
}

// ---------------- kernel 2: column partial sums of x ----------------
__global__ __launch_bounds__(256) void k_colsum(const bf16* __restrict__ x,
                                                float* __restrict__ part) {
  const int b = blockIdx.y, c = blockIdx.x;   // 32 chunks x 128 rows
  const int d = threadIdx.x * 4;
  f32x4 s = {0.f, 0.f, 0.f, 0.f};
  const bf16* base = x + ((size_t)b * 4096 + (size_t)c * 128) * 1024 + d;
  for (int i = 0; i < 128; ++i) {
    bf16x4 v = *(const bf16x4*)(base + (size_t)i * 1024);
    s[0] += (float)v[0]; s[1] += (float)v[1];
    s[2] += (float)v[2]; s[3] += (float)v[3];
  }
  *(f32x4*)(part + ((size_t)(b * 32 + c)) * 1024 + d) = s;
}

// ---------------- kernel 3: router logits -> softmax probs (1 block/batch) ----------------
__global__ __launch_bounds__(256) void k_router(const float* __restrict__ part,
                                                const float* __restrict__ rw,
                                                const float* __restrict__ rb,
                                                float* __restrict__ probs,
                                                float* __restrict__ aux) {
  const int b = blockIdx.x;
  const int t = threadIdx.x;
  __shared__ float red[4];
  __shared__ float lg[3];
  f32x4 cs = {0.f, 0.f, 0.f, 0.f};
  #pragma unroll 8
  for (int c = 0; c < 32; ++c)
    cs += *(const f32x4*)(part + ((size_t)(b * 32 + c)) * 1024 + t * 4);
  for (int e = 0; e < 3; ++e) {
    float dot = cs[0] * rw[(t*4+0)*3+e] + cs[1] * rw[(t*4+1)*3+e]
              + cs[2] * rw[(t*4+2)*3+e] + cs[3] * rw[(t*4+3)*3+e];
    for (int off = 32; off; off >>= 1) dot += __shfl_down(dot, off);
    if ((t & 63) == 0) red[t >> 6] = dot;
    __syncthreads();
    if (t == 0) lg[e] = (red[0]+red[1]+red[2]+red[3]) * (1.0f/4096.0f) + rb[e];
    __syncthreads();
  }
  if (t == 0) {
    float m = fmaxf(lg[0], fmaxf(lg[1], lg[2]));
    float p0 = __expf(lg[0]-m), p1 = __expf(lg[1]-m), p2 = __expf(lg[2]-m);
    float inv = 1.0f / (p0 + p1 + p2);
    probs[b*3+0] = p0*inv; probs[b*3+1] = p1*inv; probs[b*3+2] = p2*inv;
    if (b == 0) *aux = 0.0f;
  }
}

// ------- kernel 4: mix experts by probs + transpose -> [B][N][K] bf16 -------
__global__ __launch_bounds__(256) void k_mixT(const float* __restrict__ W,  // [3][1024][Ncols]
                                              const float* __restrict__ probs,
                                              bf16* __restrict__ out,       // [8][Ncols][1024]
                                              int Ncols) {
  const int b = blockIdx.z;
  const int i0 = blockIdx.y * 64;   // K dim (1024)
  const int j0 = blockIdx.x * 64;   // N dim (Ncols)
  const float p0 = probs[b*3+0], p1 = probs[b*3+1], p2 = probs[b*3+2];
  __shared__ float tile[64][68];
  const int t = threadIdx.x;
  const int jl = (t & 15) * 4;
  const size_t estr = (size_t)1024 * Ncols;
  for (int ii = 0; ii < 4; ++ii) {
    int il = (t >> 4) + ii * 16;
    const float* src = W + (size_t)(i0 + il) * Ncols + (j0 + jl);
    f32x4 v0 = *(const f32x4*)(src);
    f32x4 v1 = *(const f32x4*)(src + estr);
    f32x4 v2 = *(const f32x4*)(src + 2 * estr);
    f32x4 v = p0 * v0 + p1 * v1 + p2 * v2;
    tile[il][jl+0] = v[0]; tile[il][jl+1] = v[1];
    tile[il][jl+2] = v[2]; tile[il][jl+3] = v[3];
  }
  __syncthreads();
  bf16* ob = out + (size_t)b * Ncols * 1024;
  const int il2 = (t & 15) * 4;
  for (int jj = 0; jj < 4; ++jj) {
    int jl2 = (t >> 4) + jj * 16;
    bf16x4 o;
    o[0] = (bf16)tile[il2+0][jl2]; o[1] = (bf16)tile[il2+1][jl2];
    o[2] = (bf16)tile[il2+2][jl2]; o[3] = (bf16)tile[il2+3][jl2];
    *(bf16x4*)(ob + (size_t)(j0 + jl2) * 1024 + (i0 + il2)) = o;
  }
}

// ---------------- GEMM: C[M,N] = A[M,K] @ Bt[N,K]^T, bf16 MFMA ----------------
// EPI 0: GEMM1 — B rows permuted so each wave-half's ni=0,1 cols are hid(j) and
//        ni=2,3 cols are gate(j) for the SAME j: pairing is in-thread, no shuffle.
//        Epilogue computes z=sigmoid(gate), a=1-z, b=z*g(hid); writes bf16 a,b.
// EPI 1: GEMM2 — epilogue re-tiles acc through LDS, adds fp32 addend, stores fp32 C
//        fully coalesced (f32x4).
template<int EPI>
__global__ __launch_bounds__(256) void k_gemm(const bf16* __restrict__ A,
                                              const bf16* __restrict__ Bt,
                                              const float* __restrict__ addend,
                                              float* __restrict__ Cout,
                                              bf16* __restrict__ pa,
                                              bf16* __restrict__ pb,
                                              int M, int N, int K) {
  const int bz = blockIdx.z;
  const int tm = blockIdx.y, tn = blockIdx.x;
  __shared__ __align__(16) char smem[32768];
  bf16* sA = (bf16*)smem;
  bf16* sB = (bf16*)(smem + 16384);
  const int tid = threadIdx.x;
  const int lane = tid & 63, w = tid >> 6;
  const int wm = (w >> 1) * 64, wn = (w & 1) * 64;
  const int l15 = lane & 15, quad = lane >> 4;
  const bf16* Ab  = A + (size_t)bz * M * K + (size_t)tm * 128 * K;
  const bf16* Btb = Bt + (size_t)bz * N * K;
  f32x4 acc[4][4] = {};

  for (int k0 = 0; k0 < K; k0 += 64) {
    #pragma unroll
    for (int i = 0; i < 4; ++i) {
      const int q   = i * 256 + w * 64 + lane;
      const int row = q >> 3;
      const int kc  = (q & 7) ^ (row & 7);
      load16_lds(Ab + (size_t)row * K + k0 + kc * 8, (char*)sA + q * 16);
      int nrow;
      if constexpr (EPI == 0) {
        // tile col c -> j = tn*64 + (c>>6)*32 + (c&31); gate iff (c&63)>=32
        const int c = row;
        const int jloc = tn * 64 + (c >> 6) * 32 + (c & 31);
        nrow = jloc + (((c & 63) >= 32) ? 1024 : 0);
      } else {
        nrow = tn * 128 + row;
      }
      load16_lds(Btb + (size_t)nrow * K + k0 + kc * 8, (char*)sB + q * 16);
    }
    __syncthreads();
    #pragma unroll
    for (int ks = 0; ks < 2; ++ks) {
      bf16x8 af[4], bfr[4];
      const int kc = ks * 4 + quad;
      #pragma unroll
      for (int mi = 0; mi < 4; ++mi) {
        int m = wm + mi * 16 + l15;
        af[mi] = *(const bf16x8*)(sA + (size_t)(m * 8 + (kc ^ (m & 7))) * 8);
      }
      #pragma unroll
      for (int ni = 0; ni < 4; ++ni) {
        int n = wn + ni * 16 + l15;
        bfr[ni] = *(const bf16x8*)(sB + (size_t)(n * 8 + (kc ^ (n & 7))) * 8);
      }
      #pragma unroll
      for (int mi = 0; mi < 4; ++mi)
        #pragma unroll
        for (int ni = 0; ni < 4; ++ni)
          acc[mi][ni] = __builtin_amdgcn_mfma_f32_16x16x32_bf16(
              af[mi], bfr[ni], acc[mi][ni], 0, 0, 0);
    }
    __syncthreads();
  }

  if constexpr (EPI == 0) {
    // fused activation; a,b are [M][1024] per batch. In-thread hid/gate pairing:
    // hid = acc[mi][ni], gate = acc[mi][ni+2], j = tn*64 + (wn>>1) + ni*16 + l15
    bf16* Aab = pa + (size_t)bz * M * 1024;
    bf16* Bab = pb + (size_t)bz * M * 1024;
    const int jbase = tn * 64 + (wn >> 1);
    #pragma unroll
    for (int mi = 0; mi < 4; ++mi)
      #pragma unroll
      for (int ni = 0; ni < 2; ++ni)
        #pragma unroll
        for (int r = 0; r < 4; ++r) {
          int srow = tm * 128 + wm + mi * 16 + quad * 4 + r;
          float hid = acc[mi][ni][r];
          float gt  = acc[mi][ni + 2][r];
          float z = sigmoidf_(gt);
          float av = 1.0f - z;
          float gv = (hid >= 0.0f) ? (hid + 0.5f) : sigmoidf_(hid);
          float bv = z * gv;
          size_t oidx = (size_t)srow * 1024 + jbase + ni * 16 + l15;
          Aab[oidx] = (bf16)av;
          Bab[oidx] = (bf16)bv;
        }
  } else {
    // LDS-retiled coalesced epilogue: 4 passes of 32 rows
    float* sC = (float*)smem;
    const int ST = 132;                       // fp32 stride, 16B-aligned rows
    float* C = Cout + (size_t)bz * M * N;
    const float* Ain = addend + (size_t)bz * M * N;
    #pragma unroll
    for (int p = 0; p < 4; ++p) {
      __syncthreads();
      if ((wm >> 6) == (p >> 1)) {
        const int m0 = (p & 1) * 2;
        #pragma unroll
        for (int mi = m0; mi < m0 + 2; ++mi)
          #pragma unroll
          for (int ni = 0; ni < 4; ++ni)
            #pragma unroll
            for (int r = 0; r < 4; ++r) {
              int lrow = mi * 16 + quad * 4 + r - (p & 1) * 32;
              sC[lrow * ST + wn + ni * 16 + l15] = acc[mi][ni][r];
            }
      }
      __syncthreads();
      #pragma unroll
      for (int i = 0; i < 4; ++i) {
        int v = i * 256 + tid;
        int rl = v >> 5, c4 = (v & 31) * 4;
        int grow = tm * 128 + p * 32 + rl;
        int gcol = tn * 128 + c4;
        f32x4 cv = *(f32x4*)(sC + rl * ST + c4);
        f32x4 ad = *(const f32x4*)(Ain + (size_t)grow * N + gcol);
        *(f32x4*)(C + (size_t)grow * N + gcol) = cv + ad;
      }
    }
  }
}

// pass 1: per-chunk (prodA, scanB) summaries. chunks of 64 steps.
__global__ __launch_bounds__(256) void k_scan1(const bf16* __restrict__ Aab,
                                               const bf16* __restrict__ Bab,
                                               float* __restrict__ cA,
                                               float* __restrict__ cB) {
  const int b = blockIdx.y, c = blockIdx.x;
  const int d = threadIdx.x * 4;
  f32x4 A = {1.f, 1.f, 1.f, 1.f}, Bv = {0.f, 0.f, 0.f, 0.f};
  const size_t base = ((size_t)(b * 4096 + c * 64)) * 1024 + d;
  #pragma unroll 4
  for (int i = 0; i < 64; ++i) {
    bf16x4 av = *(const bf16x4*)(Aab + base + (size_t)i * 1024);
    bf16x4 bv = *(const bf16x4*)(Bab + base + (size_t)i * 1024);
    #pragma unroll
    for (int j = 0; j < 4; ++j) {
      float a = (float)av[j], bb = (float)bv[j];
      A[j] *= a; Bv[j] = a * Bv[j] + bb;
    }
  }
  *(f32x4*)(cA + ((size_t)(b * 64 + c)) * 1024 + d) = A;
  *(f32x4*)(cB + ((size_t)(b * 64 + c)) * 1024 + d) = Bv;
}

// pass 2: chunk-level prefix; writes per-chunk entry state + new_state
__global__ __launch_bounds__(256) void k_scan2(const float* __restrict__ cA,
                                               const float* __restrict__ cB,
                                               const float* __restrict__ state,
                                               float* __restrict__ hin,
                                               float* __restrict__ ns) {
  const int gid = blockIdx.x * 256 + threadIdx.x;  // 8192 channels
  const int b = gid >> 10, d = gid & 1023;
  float h = state[gid];
  for (int c0 = 0; c0 < 64; c0 += 8) {
    float ar[8], br[8];
    #pragma unroll
    for (int i = 0; i < 8; ++i) {
      size_t idx = (((size_t)(b * 64 + c0 + i)) << 10) + d;
      ar[i] = cA[idx]; br[i] = cB[idx];
    }
    #pragma unroll
    for (int i = 0; i < 8; ++i) {
      size_t idx = (((size_t)(b * 64 + c0 + i)) << 10) + d;
      hin[idx] = h;
      h = ar[i] * h + br[i];
    }
  }
  ns[gid] = h;
}

// pass 3: replay chunk with known entry state, write h (bf16)
__global__ __launch_bounds__(256) void k_scan3(const bf16* __restrict__ Aab,
                                               const bf16* __restrict__ Bab,
                                               const float* __restrict__ hin,
                                               bf16* __restrict__ hq) {
  const int b = blockIdx.y, c = blockIdx.x;
  const int d = threadIdx.x * 4;
  f32x4 h = *(const f32x4*)(hin + ((size_t)(b * 64 + c)) * 1024 + d);
  const size_t base = ((size_t)(b * 4096 + c * 64)) * 1024 + d;
  bf16* ob = hq + base;
  #pragma unroll 4
  for (int i = 0; i < 64; ++i) {
    bf16x4 av = *(const bf16x4*)(Aab + base + (size_t)i * 1024);
    bf16x4 bv = *(const bf16x4*)(Bab + base + (size_t)i * 1024);
    bf16x4 o;
    #pragma unroll
    for (int j = 0; j < 4; ++j) {
      h[j] = (float)av[j] * h[j] + (float)bv[j];
      o[j] = (bf16)h[j];
    }
    *(bf16x4*)(ob + (size_t)i * 1024) = o;
  }
}

extern "C" void kernel_launch(void* const* d_in, const int* in_sizes, int n_in,
                              void* d_out, int out_size, void* d_ws, size_t ws_size,
                              hipStream_t stream) {
  const float* inputs   = (const float*)d_in[0];
  const float* state    = (const float*)d_in[1];
  const float* norm_w   = (const float*)d_in[2];
  const float* router_w = (const float*)d_in[3];
  const float* router_b = (const float*)d_in[4];
  const float* w_gh     = (const float*)d_in[5];
  const float* w_out    = (const float*)d_in[6];

  float* out = (float*)d_out;
  float* new_state = out + (size_t)8 * 4096 * 1024;
  float* aux = new_state + 8 * 1024;

  char* ws = (char*)d_ws;
  size_t off = 0;
  auto alloc = [&](size_t bytes) {
    char* p = ws + off;
    off = (off + bytes + 255) & ~(size_t)255;
    return p;
  };
  bf16*  x    = (bf16*)alloc((size_t)8 * 4096 * 1024 * 2);   // 64 MB
  bf16*  a_ar = (bf16*)alloc((size_t)8 * 4096 * 1024 * 2);   // 64 MB
  bf16*  b_ar = (bf16*)alloc((size_t)8 * 4096 * 1024 * 2);   // 64 MB
  bf16*  hq   = (bf16*)alloc((size_t)8 * 4096 * 1024 * 2);   // 64 MB
  bf16*  WgT  = (bf16*)alloc((size_t)8 * 2048 * 1024 * 2);   // 32 MB
  bf16*  WoT  = (bf16*)alloc((size_t)8 * 1024 * 1024 * 2);   // 16 MB
  float* part = (float*)alloc((size_t)8 * 32 * 1024 * 4);    // 1 MB
  float* probs = (float*)alloc(256);
  float* cA   = (float*)alloc((size_t)8 * 64 * 1024 * 4);    // 2 MB
  float* cB   = (float*)alloc((size_t)8 * 64 * 1024 * 4);
  float* hin  = (float*)alloc((size_t)8 * 64 * 1024 * 4);
  (void)in_sizes; (void)n_in; (void)out_size; (void)ws_size;

  k_rms_x <<<32768, 256, 0, stream>>>(inputs, norm_w, x);
  k_colsum<<<dim3(32, 8), 256, 0, stream>>>(x, part);
  k_router<<<8, 256, 0, stream>>>(part, router_w, router_b, probs, aux);
  k_mixT  <<<dim3(32, 16, 8), 256, 0, stream>>>(w_gh, probs, WgT, 2048);
  k_mixT  <<<dim3(16, 16, 8), 256, 0, stream>>>(w_out, probs, WoT, 1024);
  k_gemm<0><<<dim3(16, 32, 8), 256, 0, stream>>>(x, WgT, nullptr, nullptr,
                                                 a_ar, b_ar, 4096, 2048, 1024);
  k_scan1 <<<dim3(64, 8), 256, 0, stream>>>(a_ar, b_ar, cA, cB);
  k_scan2 <<<32, 256, 0, stream>>>(cA, cB, state, hin, new_state);
  k_scan3 <<<dim3(64, 8), 256, 0, stream>>>(a_ar, b_ar, hin, hq);
  k_gemm<1><<<dim3(8, 32, 8), 256, 0, stream>>>(hq, WoT, inputs, out,
                                                nullptr, nullptr, 4096, 1024, 1024);
}